// Round 4
// baseline (3341.782 us; speedup 1.0000x reference)
//
#include <hip/hip_runtime.h>
#include <hip/hip_bf16.h>

typedef short v8s __attribute__((ext_vector_type(8)));
typedef float v4f __attribute__((ext_vector_type(4)));

#define B2ROWS 8224   /* 32*257 */
#define ROWS   16448  /* 64*257 */

// ---------------- weight prep: transpose fp32 (K x N) -> bf16 (N x K) ----------------
__global__ __launch_bounds__(256) void wprep(const float* __restrict__ W,
                                             __hip_bfloat16* __restrict__ Wt,
                                             int K, int N, int variant,
                                             const float* __restrict__ gw) {
  int k = blockIdx.x * 256 + threadIdx.x;
  int n = blockIdx.y;
  if (k >= K) return;
  float v = W[(size_t)k * N + n];
  if (variant == 1) {
    int h = k >> 6;  // head index
    float s = gw[0];
    if (h < 6 && n < 384) s += gw[1];
    if (h < 4 && n < 256) s += gw[2];
    v *= s;
  }
  Wt[(size_t)n * K + k] = __float2bfloat16(v);
}

__global__ void bias_prep(const float* __restrict__ bp, const float* __restrict__ b2,
                          const float* __restrict__ gw,
                          float* __restrict__ b_small, float* __restrict__ b2_small) {
  int c = blockIdx.x * 256 + threadIdx.x;
  if (c >= 768) return;
  float s = gw[0] + (c < 384 ? gw[1] : 0.f) + (c < 256 ? gw[2] : 0.f);
  b_small[c] = bp[c] * s;
  b2_small[c] = b2[c] * s;
}

// ---------------- LayerNorm: fp32 in -> bf16 out, one row per wave ----------------
__global__ __launch_bounds__(256) void ln_k(const float* __restrict__ X,
                                            __hip_bfloat16* __restrict__ out,
                                            const float* __restrict__ gl, const float* __restrict__ bl,
                                            const float* __restrict__ gs, const float* __restrict__ bs) {
  int wave = threadIdx.x >> 6, lane = threadIdx.x & 63;
  int row = blockIdx.x * 4 + wave;
  const float* g = (row < B2ROWS) ? gl : gs;
  const float* b = (row < B2ROWS) ? bl : bs;
  const float* xr = X + (size_t)row * 768;
  float v[12]; float s = 0.f, ss = 0.f;
#pragma unroll
  for (int i = 0; i < 12; i++) { v[i] = xr[lane + i * 64]; s += v[i]; ss += v[i] * v[i]; }
#pragma unroll
  for (int o = 32; o > 0; o >>= 1) { s += __shfl_xor(s, o, 64); ss += __shfl_xor(ss, o, 64); }
  float mean = s * (1.0f / 768.0f);
  float var = ss * (1.0f / 768.0f) - mean * mean;
  float rstd = rsqrtf(var + 1e-5f);
  __hip_bfloat16* orow = out + (size_t)row * 768;
#pragma unroll
  for (int i = 0; i < 12; i++) {
    int c = lane + i * 64;
    orow[c] = __float2bfloat16((v[i] - mean) * rstd * g[c] + b[c]);
  }
}

// ---------------- bf16 MFMA GEMM v2: global_load_lds + swizzled LDS, BMx256 tile ----
// C(MxN) = A(MxK) * Bt(NxK)^T
// mode 0: out bf16 = acc
// mode 1: out bf16 = scale*gelu(acc + bias) + (addin ? addin : 0)   (addin may alias out)
// mode 2: out fp32 = acc + bias + resid                             (resid may alias out)
// LDS layout: [row][kchunk] 64 B/row, with kchunk position XOR-swizzled by
// (row>>1)&3. global_load_lds writes lane-contiguous (row=lane>>2, pos=lane&3),
// so the swizzle is applied to the per-lane SOURCE k-offset (qs below).
template<int WM, int WN, int IT, int JT>
__global__ __launch_bounds__(256, 2) void gemm2(
    const __hip_bfloat16* __restrict__ A, int lda,
    const __hip_bfloat16* __restrict__ Bt, int ldb,
    int M, int Nlim, int K,
    const float* __restrict__ bias,
    const float* __restrict__ resid, int ldr,
    const float* __restrict__ gw, int gidx,
    const __hip_bfloat16* __restrict__ addin,
    void* __restrict__ out, int ldo,
    int mode) {
  constexpr int BM = WM * IT * 16;
  constexpr int BN = WN * JT * 16;   // always 256
  constexpr int CA = BM / 16;        // A chunks of 16 rows
  __shared__ __attribute__((aligned(16))) short As[BM * 32];
  __shared__ __attribute__((aligned(16))) short Bs[BN * 32];
  int tid = threadIdx.x;
  int lane = tid & 63, w = tid >> 6;
  int l16 = lane & 15, quad = lane >> 4;
  int wm = w / WN, wn = w % WN;
  int m0 = blockIdx.x * BM, n0 = blockIdx.y * BN;
  int r4 = lane >> 2;
  int qs = (lane & 3) ^ ((lane >> 3) & 3);   // swizzled source k-chunk
  int sw = (quad ^ ((l16 >> 1) & 3)) * 8;    // swizzled read offset (shorts)

  v4f acc[IT][JT];
#pragma unroll
  for (int i = 0; i < IT; i++)
#pragma unroll
    for (int j = 0; j < JT; j++) acc[i][j] = (v4f){0.f, 0.f, 0.f, 0.f};

  const ushort* Au = (const ushort*)A;
  const ushort* Bu = (const ushort*)Bt;

  for (int k0 = 0; k0 < K; k0 += 32) {
    __syncthreads();
#pragma unroll
    for (int c = 0; c < CA / 4; c++) {
      int ch = w * (CA / 4) + c;
      int grow = m0 + ch * 16 + r4; if (grow >= M) grow = M - 1;
      const void* g = Au + (size_t)grow * lda + k0 + qs * 8;
      __builtin_amdgcn_global_load_lds(
          (const __attribute__((address_space(1))) uint32_t*)(uintptr_t)g,
          (__attribute__((address_space(3))) uint32_t*)(uint32_t)(uintptr_t)(const void*)&As[ch * 512],
          16, 0, 0);
    }
#pragma unroll
    for (int c = 0; c < 4; c++) {
      int ch = w * 4 + c;
      int gn = n0 + ch * 16 + r4; if (gn >= Nlim) gn = Nlim - 1;
      const void* g = Bu + (size_t)gn * ldb + k0 + qs * 8;
      __builtin_amdgcn_global_load_lds(
          (const __attribute__((address_space(1))) uint32_t*)(uintptr_t)g,
          (__attribute__((address_space(3))) uint32_t*)(uint32_t)(uintptr_t)(const void*)&Bs[ch * 512],
          16, 0, 0);
    }
    __syncthreads();
    v8s af[IT], bf[JT];
#pragma unroll
    for (int i = 0; i < IT; i++) {
      int R = wm * IT * 16 + i * 16 + l16;
      af[i] = *(const v8s*)&As[R * 32 + sw];
    }
#pragma unroll
    for (int j = 0; j < JT; j++) {
      int R = wn * JT * 16 + j * 16 + l16;
      bf[j] = *(const v8s*)&Bs[R * 32 + sw];
    }
#pragma unroll
    for (int i = 0; i < IT; i++)
#pragma unroll
      for (int j = 0; j < JT; j++)
        acc[i][j] = __builtin_amdgcn_mfma_f32_16x16x32_bf16(af[i], bf[j], acc[i][j], 0, 0, 0);
  }

  float scale = (gidx >= 0) ? gw[gidx] : 1.0f;

#pragma unroll
  for (int i = 0; i < IT; i++) {
#pragma unroll
    for (int j = 0; j < JT; j++) {
      int gc = n0 + wn * JT * 16 + j * 16 + l16;
      if (gc >= Nlim) continue;
#pragma unroll
      for (int r = 0; r < 4; r++) {
        int gr = m0 + wm * IT * 16 + i * 16 + quad * 4 + r;
        if (gr < M) {
          float v = acc[i][j][r];
          if (mode == 0) {
            ((__hip_bfloat16*)out)[(size_t)gr * ldo + gc] = __float2bfloat16(v);
          } else if (mode == 1) {
            float z = v + bias[gc];
            float gl = 0.5f * z * (1.0f + erff(z * 0.70710678118654752f));
            float res = scale * gl;
            if (addin) res += __bfloat162float(addin[(size_t)gr * ldo + gc]);
            ((__hip_bfloat16*)out)[(size_t)gr * ldo + gc] = __float2bfloat16(res);
          } else {
            float z = v + bias[gc] + resid[(size_t)gr * ldr + gc];
            ((float*)out)[(size_t)gr * ldo + gc] = z;
          }
        }
      }
    }
  }
}

// ---------------- MFMA flash attention (unchanged from round 3) ----------------
__global__ __launch_bounds__(256) void attn_k(const __hip_bfloat16* __restrict__ qkv,
                                              __hip_bfloat16* __restrict__ O) {
  __shared__ ushort Ks[64 * 72];
  __shared__ ushort Vs[64 * 64];
  __shared__ ushort Ps[4][16 * 72];
  int bh = blockIdx.x;
  int b = bh / 12, h = bh % 12;
  size_t base = (size_t)b * 257;
  const ushort* Qg = (const ushort*)qkv;
  int tid = threadIdx.x;
  int w = tid >> 6, lane = tid & 63;
  int l16 = lane & 15, quad = lane >> 4;
  int qrow0 = blockIdx.y * 64 + w * 16;

  v8s aq[2];
  {
    int gr = qrow0 + l16; if (gr > 256) gr = 256;
    const ushort* qp = Qg + (base + gr) * 2304 + h * 64;
    aq[0] = *(const v8s*)(qp + quad * 8);
    aq[1] = *(const v8s*)(qp + 32 + quad * 8);
  }

  float mrow[4], lrow[4];
  v4f o[4];
#pragma unroll
  for (int r = 0; r < 4; r++) { mrow[r] = -1e30f; lrow[r] = 0.f; }
#pragma unroll
  for (int dt = 0; dt < 4; dt++) o[dt] = (v4f){0.f, 0.f, 0.f, 0.f};

  for (int kt = 0; kt < 5; kt++) {
    __syncthreads();
#pragma unroll
    for (int it = 0; it < 2; it++) {
      int ch = tid + it * 256;
      int row = ch >> 3, oct = ch & 7;
      int gk = kt * 64 + row; if (gk > 256) gk = 256;
      *(uint4*)&Ks[row * 72 + oct * 8] =
        *(const uint4*)(Qg + (base + gk) * 2304 + 768 + h * 64 + oct * 8);
    }
#pragma unroll
    for (int it = 0; it < 2; it++) {
      int oct = w + it * 4;
      int gk = kt * 64 + lane; if (gk > 256) gk = 256;
      ushort tmp[8];
      *(uint4*)tmp = *(const uint4*)(Qg + (base + gk) * 2304 + 1536 + h * 64 + oct * 8);
#pragma unroll
      for (int j = 0; j < 8; j++) {
        int d = oct * 8 + j;
        Vs[d * 64 + (((lane >> 3) ^ j) * 8) + (lane & 7)] = tmp[j];
      }
    }
    __syncthreads();

    v4f s[4];
#pragma unroll
    for (int jt = 0; jt < 4; jt++) {
      v8s bk0 = *(const v8s*)&Ks[(jt * 16 + l16) * 72 + quad * 8];
      v8s bk1 = *(const v8s*)&Ks[(jt * 16 + l16) * 72 + 32 + quad * 8];
      v4f acc = (v4f){0.f, 0.f, 0.f, 0.f};
      acc = __builtin_amdgcn_mfma_f32_16x16x32_bf16(aq[0], bk0, acc, 0, 0, 0);
      acc = __builtin_amdgcn_mfma_f32_16x16x32_bf16(aq[1], bk1, acc, 0, 0, 0);
      s[jt] = acc;
    }
#pragma unroll
    for (int jt = 0; jt < 4; jt++) {
      int col = kt * 64 + jt * 16 + l16;
      bool valid = col < 257;
#pragma unroll
      for (int r = 0; r < 4; r++)
        s[jt][r] = valid ? s[jt][r] * 0.125f : -1e30f;
    }
    float mnew[4], alpha[4], psum[4];
#pragma unroll
    for (int r = 0; r < 4; r++) {
      float mx = fmaxf(fmaxf(s[0][r], s[1][r]), fmaxf(s[2][r], s[3][r]));
#pragma unroll
      for (int off = 1; off < 16; off <<= 1) mx = fmaxf(mx, __shfl_xor(mx, off, 64));
      mnew[r] = fmaxf(mrow[r], mx);
      alpha[r] = __expf(mrow[r] - mnew[r]);
      mrow[r] = mnew[r];
      psum[r] = 0.f;
    }
#pragma unroll
    for (int jt = 0; jt < 4; jt++) {
#pragma unroll
      for (int r = 0; r < 4; r++) {
        float p = __expf(s[jt][r] - mnew[r]);
        psum[r] += p;
        __hip_bfloat16 pb = __float2bfloat16(p);
        Ps[w][(quad * 4 + r) * 72 + jt * 16 + l16] = *(ushort*)&pb;
      }
    }
#pragma unroll
    for (int r = 0; r < 4; r++) {
#pragma unroll
      for (int off = 1; off < 16; off <<= 1) psum[r] += __shfl_xor(psum[r], off, 64);
      lrow[r] = lrow[r] * alpha[r] + psum[r];
    }
#pragma unroll
    for (int dt = 0; dt < 4; dt++)
#pragma unroll
      for (int r = 0; r < 4; r++) o[dt][r] *= alpha[r];
    v8s pa0 = *(const v8s*)&Ps[w][l16 * 72 + quad * 8];
    v8s pa1 = *(const v8s*)&Ps[w][l16 * 72 + 32 + quad * 8];
#pragma unroll
    for (int dt = 0; dt < 4; dt++) {
      int d = dt * 16 + l16;
      v8s bv0 = *(const v8s*)&Vs[d * 64 + ((quad ^ (d & 7)) * 8)];
      v8s bv1 = *(const v8s*)&Vs[d * 64 + (((4 + quad) ^ (d & 7)) * 8)];
      o[dt] = __builtin_amdgcn_mfma_f32_16x16x32_bf16(pa0, bv0, o[dt], 0, 0, 0);
      o[dt] = __builtin_amdgcn_mfma_f32_16x16x32_bf16(pa1, bv1, o[dt], 0, 0, 0);
    }
  }
#pragma unroll
  for (int r = 0; r < 4; r++) {
    int gr = qrow0 + quad * 4 + r;
    if (gr < 257) {
      float inv = 1.f / lrow[r];
      __hip_bfloat16* orow = O + (base + gr) * 768 + h * 64;
#pragma unroll
      for (int dt = 0; dt < 4; dt++)
        orow[dt * 16 + l16] = __float2bfloat16(o[dt][r] * inv);
    }
  }
}

extern "C" void kernel_launch(void* const* d_in, const int* in_sizes, int n_in,
                              void* d_out, int out_size, void* d_ws, size_t ws_size,
                              hipStream_t stream) {
  const float* x      = (const float*)d_in[0];
  const float* gw     = (const float*)d_in[1];
  const float* n1l_g  = (const float*)d_in[2];
  const float* n1l_b  = (const float*)d_in[3];
  const float* n1s_g  = (const float*)d_in[4];
  const float* n1s_b  = (const float*)d_in[5];
  const float* w_qkv  = (const float*)d_in[6];
  const float* w_proj = (const float*)d_in[7];
  const float* b_proj = (const float*)d_in[8];
  const float* n2l_g  = (const float*)d_in[9];
  const float* n2l_b  = (const float*)d_in[10];
  const float* n2s_g  = (const float*)d_in[11];
  const float* n2s_b  = (const float*)d_in[12];
  const float* w_fc1  = (const float*)d_in[13];
  const float* b_fc1  = (const float*)d_in[14];
  const float* w_fc2  = (const float*)d_in[15];
  const float* b_fc2  = (const float*)d_in[16];
  float* out = (float*)d_out;

  const size_t REQUIRED = (size_t)(2304*768 + 2*768*768 + 2*3072*768) * 2
                        + 2 * 768 * 4 + 512
                        + (size_t)ROWS * 768 * 2
                        + (size_t)ROWS * 2304 * 2;
  if (ws_size < REQUIRED) return;

  char* ws = (char*)d_ws;
  size_t off = 0;
  auto alloc = [&](size_t bytes) -> void* {
    void* p = ws + off;
    off = (off + bytes + 255) & ~(size_t)255;
    return p;
  };
  __hip_bfloat16* wqkv_t  = (__hip_bfloat16*)alloc((size_t)2304 * 768 * 2);
  __hip_bfloat16* wproj_l = (__hip_bfloat16*)alloc((size_t)768 * 768 * 2);
  __hip_bfloat16* wproj_s = (__hip_bfloat16*)alloc((size_t)768 * 768 * 2);
  __hip_bfloat16* wfc1_t  = (__hip_bfloat16*)alloc((size_t)3072 * 768 * 2);
  __hip_bfloat16* wfc2_t  = (__hip_bfloat16*)alloc((size_t)768 * 3072 * 2);
  float* b_small  = (float*)alloc(768 * 4);
  float* b2_small = (float*)alloc(768 * 4);
  __hip_bfloat16* xn   = (__hip_bfloat16*)alloc((size_t)ROWS * 768 * 2);   // also O after attention
  __hip_bfloat16* qkv  = (__hip_bfloat16*)alloc((size_t)ROWS * 2304 * 2);  // also xn2 + hbuf
  __hip_bfloat16* Obuf = xn;
  __hip_bfloat16* xn2  = qkv;
  __hip_bfloat16* hbuf = qkv + (size_t)ROWS * 768;  // 8224*3072 bf16 exactly

  // ---- weight / bias prep ----
  wprep<<<dim3(3, 2304), 256, 0, stream>>>(w_qkv, wqkv_t, 768, 2304, 0, gw);
  wprep<<<dim3(3, 768),  256, 0, stream>>>(w_proj, wproj_l, 768, 768, 0, gw);
  wprep<<<dim3(3, 768),  256, 0, stream>>>(w_proj, wproj_s, 768, 768, 1, gw);
  wprep<<<dim3(3, 3072), 256, 0, stream>>>(w_fc1, wfc1_t, 768, 3072, 0, gw);
  wprep<<<dim3(12, 768), 256, 0, stream>>>(w_fc2, wfc2_t, 3072, 768, 0, gw);
  bias_prep<<<3, 256, 0, stream>>>(b_proj, b_fc2, gw, b_small, b2_small);

  // ---- LN1 ----
  ln_k<<<ROWS / 4, 256, 0, stream>>>(x, xn, n1l_g, n1l_b, n1s_g, n1s_b);

  // ---- QKV: 128x256 tiles ----
  gemm2<2,2,4,8><<<dim3(129, 9), 256, 0, stream>>>(
      xn, 768, wqkv_t, 768, ROWS, 2304, 768,
      nullptr, nullptr, 0, gw, -1, nullptr, qkv, 2304, 0);

  // ---- attention (MFMA flash) ----
  attn_k<<<dim3(768, 5), 256, 0, stream>>>(qkv, Obuf);

  // ---- proj + residual -> x1 in d_out (fp32); 64x256 tiles ----
  gemm2<1,4,4,4><<<dim3(129, 3), 256, 0, stream>>>(
      Obuf, 768, wproj_l, 768, B2ROWS, 768, 768,
      b_proj, x, 768, gw, -1, nullptr, out, 768, 2);
  gemm2<1,4,4,4><<<dim3(129, 3), 256, 0, stream>>>(
      Obuf + (size_t)B2ROWS * 768, 768, wproj_s, 768, B2ROWS, 768, 768,
      b_small, x + (size_t)B2ROWS * 768, 768, gw, -1, nullptr,
      out + (size_t)B2ROWS * 768, 768, 2);

  // ---- LN2 on x1 (qkv region reused as xn2 + hbuf) ----
  ln_k<<<ROWS / 4, 256, 0, stream>>>(out, xn2, n2l_g, n2l_b, n2s_g, n2s_b);
  const __hip_bfloat16* xn2s = xn2 + (size_t)B2ROWS * 768;
  float* outs = out + (size_t)B2ROWS * 768;

  // ---- large MLP ----
  gemm2<2,2,4,8><<<dim3(65, 12), 256, 0, stream>>>(
      xn2, 768, wfc1_t, 768, B2ROWS, 3072, 768,
      b_fc1, nullptr, 0, gw, -1, nullptr, hbuf, 3072, 1);
  gemm2<1,4,4,4><<<dim3(129, 3), 256, 0, stream>>>(
      hbuf, 3072, wfc2_t, 3072, B2ROWS, 768, 3072,
      b_fc2, out, 768, gw, -1, nullptr, out, 768, 2);

  // ---- small MLP: prefix chain in hbuf, FC2 per column slab ----
  gemm2<2,2,4,8><<<dim3(65, 12), 256, 0, stream>>>(
      xn2s, 768, wfc1_t, 768, B2ROWS, 3072, 768,
      b_fc1, nullptr, 0, gw, 0, nullptr, hbuf, 3072, 1);
  gemm2<1,4,4,4><<<dim3(129, 2), 256, 0, stream>>>(
      hbuf, 3072, wfc2_t + (size_t)384 * 3072, 3072, B2ROWS, 384, 3072,
      b2_small + 384, outs + 384, 768, gw, -1, nullptr, outs + 384, 768, 2);
  gemm2<2,2,4,8><<<dim3(65, 12), 256, 0, stream>>>(
      xn2s, 768, wfc1_t, 768, B2ROWS, 3072, 384,
      b_fc1, nullptr, 0, gw, 1, hbuf, hbuf, 3072, 1);
  gemm2<1,4,4,4><<<dim3(129, 1), 256, 0, stream>>>(
      hbuf, 3072, wfc2_t + (size_t)256 * 3072, 3072, B2ROWS, 128, 3072,
      b2_small + 256, outs + 256, 768, gw, -1, nullptr, outs + 256, 768, 2);
  gemm2<2,2,4,8><<<dim3(65, 12), 256, 0, stream>>>(
      xn2s, 768, wfc1_t, 768, B2ROWS, 3072, 256,
      b_fc1, nullptr, 0, gw, 2, hbuf, hbuf, 3072, 1);
  gemm2<1,4,4,4><<<dim3(129, 1), 256, 0, stream>>>(
      hbuf, 3072, wfc2_t, 3072, B2ROWS, 256, 3072,
      b2_small, outs, 768, gw, -1, nullptr, outs, 768, 2);
}

// Round 5
// 1247.989 us; speedup vs baseline: 2.6777x; 2.6777x over previous
//
#include <hip/hip_runtime.h>
#include <hip/hip_bf16.h>

typedef short v8s __attribute__((ext_vector_type(8)));
typedef float v4f __attribute__((ext_vector_type(4)));

#define B2ROWS 8224   /* 32*257 */
#define ROWS   16448  /* 64*257 */

// ---------------- weight prep: transpose fp32 (K x N) -> bf16 (N x K) ----------------
__global__ __launch_bounds__(256) void wprep(const float* __restrict__ W,
                                             __hip_bfloat16* __restrict__ Wt,
                                             int K, int N, int variant,
                                             const float* __restrict__ gw) {
  int k = blockIdx.x * 256 + threadIdx.x;
  int n = blockIdx.y;
  if (k >= K) return;
  float v = W[(size_t)k * N + n];
  if (variant == 1) {
    int h = k >> 6;  // head index
    float s = gw[0];
    if (h < 6 && n < 384) s += gw[1];
    if (h < 4 && n < 256) s += gw[2];
    v *= s;
  }
  Wt[(size_t)n * K + k] = __float2bfloat16(v);
}

__global__ void bias_prep(const float* __restrict__ bp, const float* __restrict__ b2,
                          const float* __restrict__ gw,
                          float* __restrict__ b_small, float* __restrict__ b2_small) {
  int c = blockIdx.x * 256 + threadIdx.x;
  if (c >= 768) return;
  float s = gw[0] + (c < 384 ? gw[1] : 0.f) + (c < 256 ? gw[2] : 0.f);
  b_small[c] = bp[c] * s;
  b2_small[c] = b2[c] * s;
}

// ---------------- LayerNorm: fp32 in -> bf16 out, one row per wave ----------------
__global__ __launch_bounds__(256) void ln_k(const float* __restrict__ X,
                                            __hip_bfloat16* __restrict__ out,
                                            const float* __restrict__ gl, const float* __restrict__ bl,
                                            const float* __restrict__ gs, const float* __restrict__ bs) {
  int wave = threadIdx.x >> 6, lane = threadIdx.x & 63;
  int row = blockIdx.x * 4 + wave;
  const float* g = (row < B2ROWS) ? gl : gs;
  const float* b = (row < B2ROWS) ? bl : bs;
  const float* xr = X + (size_t)row * 768;
  float v[12]; float s = 0.f, ss = 0.f;
#pragma unroll
  for (int i = 0; i < 12; i++) { v[i] = xr[lane + i * 64]; s += v[i]; ss += v[i] * v[i]; }
#pragma unroll
  for (int o = 32; o > 0; o >>= 1) { s += __shfl_xor(s, o, 64); ss += __shfl_xor(ss, o, 64); }
  float mean = s * (1.0f / 768.0f);
  float var = ss * (1.0f / 768.0f) - mean * mean;
  float rstd = rsqrtf(var + 1e-5f);
  __hip_bfloat16* orow = out + (size_t)row * 768;
#pragma unroll
  for (int i = 0; i < 12; i++) {
    int c = lane + i * 64;
    orow[c] = __float2bfloat16((v[i] - mean) * rstd * g[c] + b[c]);
  }
}

// ---------------- bf16 MFMA GEMM: C(MxN) = A(MxK) * Bt(NxK)^T, 128x128 tile ----------------
// blockIdx.x = n-group (fast: co-resident blocks share A row-blocks in L2/L3)
// blockIdx.y = m-group
// LDS: 32 shorts/row, 16-B chunk q of row r stored at position q^((r>>1)&3)
// -> fragment ds_read_b128 covers all 32 banks once per 8 lanes (2-way = free).
// mode 0: out bf16 = acc
// mode 1: out bf16 = scale*gelu(acc + bias) + (addin ? addin : 0)   (addin may alias out)
// mode 2: out fp32 = acc + bias + resid                             (resid may alias out)
__global__ __launch_bounds__(256) void gemm_k(
    const __hip_bfloat16* __restrict__ A, int lda,
    const __hip_bfloat16* __restrict__ Bt, int ldb,
    int M, int K,
    const float* __restrict__ bias,
    const float* __restrict__ resid, int ldr,
    const float* __restrict__ gw, int gidx,
    const __hip_bfloat16* __restrict__ addin,
    void* __restrict__ out, int ldo,
    int mode) {
  __shared__ __attribute__((aligned(16))) short As[128 * 32];
  __shared__ __attribute__((aligned(16))) short Bs[128 * 32];
  int tid = threadIdx.x;
  int lane = tid & 63;
  int wave = tid >> 6;
  int wm = wave >> 1, wn = wave & 1;
  int l16 = lane & 15, quad = lane >> 4;
  int m0 = blockIdx.y * 128, n0 = blockIdx.x * 128;
  int sw = (quad ^ ((l16 >> 1) & 3)) * 8;   // swizzled read chunk offset (shorts)

  v4f acc[4][4];
#pragma unroll
  for (int i = 0; i < 4; i++)
#pragma unroll
    for (int j = 0; j < 4; j++) acc[i][j] = (v4f){0.f, 0.f, 0.f, 0.f};

  const ushort* Au = (const ushort*)A;
  const ushort* Bu = (const ushort*)Bt;

  for (int k0 = 0; k0 < K; k0 += 32) {
    __syncthreads();
#pragma unroll
    for (int it = 0; it < 2; it++) {
      int ch = tid + it * 256;
      int r = ch >> 2, q = ch & 3;
      int p = q ^ ((r >> 1) & 3);           // swizzled write position
      int gr = m0 + r; if (gr > M - 1) gr = M - 1;  // clamp (finite garbage, store-masked)
      *(uint4*)&As[r * 32 + p * 8] = *(const uint4*)(Au + (size_t)gr * lda + k0 + q * 8);
      int gn = n0 + r;  // N always a multiple of 128
      *(uint4*)&Bs[r * 32 + p * 8] = *(const uint4*)(Bu + (size_t)gn * ldb + k0 + q * 8);
    }
    __syncthreads();
    v8s af[4], bfr[4];
#pragma unroll
    for (int i = 0; i < 4; i++) af[i] = *(const v8s*)&As[(wm * 64 + i * 16 + l16) * 32 + sw];
#pragma unroll
    for (int j = 0; j < 4; j++) bfr[j] = *(const v8s*)&Bs[(wn * 64 + j * 16 + l16) * 32 + sw];
#pragma unroll
    for (int i = 0; i < 4; i++)
#pragma unroll
      for (int j = 0; j < 4; j++)
        acc[i][j] = __builtin_amdgcn_mfma_f32_16x16x32_bf16(af[i], bfr[j], acc[i][j], 0, 0, 0);
  }

  float scale = (gidx >= 0) ? gw[gidx] : 1.0f;

#pragma unroll
  for (int i = 0; i < 4; i++) {
#pragma unroll
    for (int j = 0; j < 4; j++) {
      int gc = n0 + wn * 64 + j * 16 + l16;
#pragma unroll
      for (int r = 0; r < 4; r++) {
        int gr = m0 + wm * 64 + i * 16 + quad * 4 + r;
        if (gr < M) {
          float v = acc[i][j][r];
          if (mode == 0) {
            ((__hip_bfloat16*)out)[(size_t)gr * ldo + gc] = __float2bfloat16(v);
          } else if (mode == 1) {
            float z = v + bias[gc];
            float gl = 0.5f * z * (1.0f + erff(z * 0.70710678118654752f));
            float res = scale * gl;
            if (addin) res += __bfloat162float(addin[(size_t)gr * ldo + gc]);
            ((__hip_bfloat16*)out)[(size_t)gr * ldo + gc] = __float2bfloat16(res);
          } else {
            float z = v + bias[gc] + resid[(size_t)gr * ldr + gc];
            ((float*)out)[(size_t)gr * ldo + gc] = z;
          }
        }
      }
    }
  }
}

// ---------------- MFMA flash attention (unchanged) ----------------
__global__ __launch_bounds__(256) void attn_k(const __hip_bfloat16* __restrict__ qkv,
                                              __hip_bfloat16* __restrict__ O) {
  __shared__ ushort Ks[64 * 72];
  __shared__ ushort Vs[64 * 64];
  __shared__ ushort Ps[4][16 * 72];
  int bh = blockIdx.x;
  int b = bh / 12, h = bh % 12;
  size_t base = (size_t)b * 257;
  const ushort* Qg = (const ushort*)qkv;
  int tid = threadIdx.x;
  int w = tid >> 6, lane = tid & 63;
  int l16 = lane & 15, quad = lane >> 4;
  int qrow0 = blockIdx.y * 64 + w * 16;

  v8s aq[2];
  {
    int gr = qrow0 + l16; if (gr > 256) gr = 256;
    const ushort* qp = Qg + (base + gr) * 2304 + h * 64;
    aq[0] = *(const v8s*)(qp + quad * 8);
    aq[1] = *(const v8s*)(qp + 32 + quad * 8);
  }

  float mrow[4], lrow[4];
  v4f o[4];
#pragma unroll
  for (int r = 0; r < 4; r++) { mrow[r] = -1e30f; lrow[r] = 0.f; }
#pragma unroll
  for (int dt = 0; dt < 4; dt++) o[dt] = (v4f){0.f, 0.f, 0.f, 0.f};

  for (int kt = 0; kt < 5; kt++) {
    __syncthreads();
#pragma unroll
    for (int it = 0; it < 2; it++) {
      int ch = tid + it * 256;
      int row = ch >> 3, oct = ch & 7;
      int gk = kt * 64 + row; if (gk > 256) gk = 256;
      *(uint4*)&Ks[row * 72 + oct * 8] =
        *(const uint4*)(Qg + (base + gk) * 2304 + 768 + h * 64 + oct * 8);
    }
#pragma unroll
    for (int it = 0; it < 2; it++) {
      int oct = w + it * 4;
      int gk = kt * 64 + lane; if (gk > 256) gk = 256;
      ushort tmp[8];
      *(uint4*)tmp = *(const uint4*)(Qg + (base + gk) * 2304 + 1536 + h * 64 + oct * 8);
#pragma unroll
      for (int j = 0; j < 8; j++) {
        int d = oct * 8 + j;
        Vs[d * 64 + (((lane >> 3) ^ j) * 8) + (lane & 7)] = tmp[j];
      }
    }
    __syncthreads();

    v4f s[4];
#pragma unroll
    for (int jt = 0; jt < 4; jt++) {
      v8s bk0 = *(const v8s*)&Ks[(jt * 16 + l16) * 72 + quad * 8];
      v8s bk1 = *(const v8s*)&Ks[(jt * 16 + l16) * 72 + 32 + quad * 8];
      v4f acc = (v4f){0.f, 0.f, 0.f, 0.f};
      acc = __builtin_amdgcn_mfma_f32_16x16x32_bf16(aq[0], bk0, acc, 0, 0, 0);
      acc = __builtin_amdgcn_mfma_f32_16x16x32_bf16(aq[1], bk1, acc, 0, 0, 0);
      s[jt] = acc;
    }
#pragma unroll
    for (int jt = 0; jt < 4; jt++) {
      int col = kt * 64 + jt * 16 + l16;
      bool valid = col < 257;
#pragma unroll
      for (int r = 0; r < 4; r++)
        s[jt][r] = valid ? s[jt][r] * 0.125f : -1e30f;
    }
    float mnew[4], alpha[4], psum[4];
#pragma unroll
    for (int r = 0; r < 4; r++) {
      float mx = fmaxf(fmaxf(s[0][r], s[1][r]), fmaxf(s[2][r], s[3][r]));
#pragma unroll
      for (int off = 1; off < 16; off <<= 1) mx = fmaxf(mx, __shfl_xor(mx, off, 64));
      mnew[r] = fmaxf(mrow[r], mx);
      alpha[r] = __expf(mrow[r] - mnew[r]);
      mrow[r] = mnew[r];
      psum[r] = 0.f;
    }
#pragma unroll
    for (int jt = 0; jt < 4; jt++) {
#pragma unroll
      for (int r = 0; r < 4; r++) {
        float p = __expf(s[jt][r] - mnew[r]);
        psum[r] += p;
        __hip_bfloat16 pb = __float2bfloat16(p);
        Ps[w][(quad * 4 + r) * 72 + jt * 16 + l16] = *(ushort*)&pb;
      }
    }
#pragma unroll
    for (int r = 0; r < 4; r++) {
#pragma unroll
      for (int off = 1; off < 16; off <<= 1) psum[r] += __shfl_xor(psum[r], off, 64);
      lrow[r] = lrow[r] * alpha[r] + psum[r];
    }
#pragma unroll
    for (int dt = 0; dt < 4; dt++)
#pragma unroll
      for (int r = 0; r < 4; r++) o[dt][r] *= alpha[r];
    v8s pa0 = *(const v8s*)&Ps[w][l16 * 72 + quad * 8];
    v8s pa1 = *(const v8s*)&Ps[w][l16 * 72 + 32 + quad * 8];
#pragma unroll
    for (int dt = 0; dt < 4; dt++) {
      int d = dt * 16 + l16;
      v8s bv0 = *(const v8s*)&Vs[d * 64 + ((quad ^ (d & 7)) * 8)];
      v8s bv1 = *(const v8s*)&Vs[d * 64 + (((4 + quad) ^ (d & 7)) * 8)];
      o[dt] = __builtin_amdgcn_mfma_f32_16x16x32_bf16(pa0, bv0, o[dt], 0, 0, 0);
      o[dt] = __builtin_amdgcn_mfma_f32_16x16x32_bf16(pa1, bv1, o[dt], 0, 0, 0);
    }
  }
#pragma unroll
  for (int r = 0; r < 4; r++) {
    int gr = qrow0 + quad * 4 + r;
    if (gr < 257) {
      float inv = 1.f / lrow[r];
      __hip_bfloat16* orow = O + (base + gr) * 768 + h * 64;
#pragma unroll
      for (int dt = 0; dt < 4; dt++)
        orow[dt * 16 + l16] = __float2bfloat16(o[dt][r] * inv);
    }
  }
}

extern "C" void kernel_launch(void* const* d_in, const int* in_sizes, int n_in,
                              void* d_out, int out_size, void* d_ws, size_t ws_size,
                              hipStream_t stream) {
  const float* x      = (const float*)d_in[0];
  const float* gw     = (const float*)d_in[1];
  const float* n1l_g  = (const float*)d_in[2];
  const float* n1l_b  = (const float*)d_in[3];
  const float* n1s_g  = (const float*)d_in[4];
  const float* n1s_b  = (const float*)d_in[5];
  const float* w_qkv  = (const float*)d_in[6];
  const float* w_proj = (const float*)d_in[7];
  const float* b_proj = (const float*)d_in[8];
  const float* n2l_g  = (const float*)d_in[9];
  const float* n2l_b  = (const float*)d_in[10];
  const float* n2s_g  = (const float*)d_in[11];
  const float* n2s_b  = (const float*)d_in[12];
  const float* w_fc1  = (const float*)d_in[13];
  const float* b_fc1  = (const float*)d_in[14];
  const float* w_fc2  = (const float*)d_in[15];
  const float* b_fc2  = (const float*)d_in[16];
  float* out = (float*)d_out;

  const size_t REQUIRED = (size_t)(2304*768 + 2*768*768 + 2*3072*768) * 2
                        + 2 * 768 * 4 + 512
                        + (size_t)ROWS * 768 * 2
                        + (size_t)ROWS * 2304 * 2;
  if (ws_size < REQUIRED) return;

  char* ws = (char*)d_ws;
  size_t off = 0;
  auto alloc = [&](size_t bytes) -> void* {
    void* p = ws + off;
    off = (off + bytes + 255) & ~(size_t)255;
    return p;
  };
  __hip_bfloat16* wqkv_t  = (__hip_bfloat16*)alloc((size_t)2304 * 768 * 2);
  __hip_bfloat16* wproj_l = (__hip_bfloat16*)alloc((size_t)768 * 768 * 2);
  __hip_bfloat16* wproj_s = (__hip_bfloat16*)alloc((size_t)768 * 768 * 2);
  __hip_bfloat16* wfc1_t  = (__hip_bfloat16*)alloc((size_t)3072 * 768 * 2);
  __hip_bfloat16* wfc2_t  = (__hip_bfloat16*)alloc((size_t)768 * 3072 * 2);
  float* b_small  = (float*)alloc(768 * 4);
  float* b2_small = (float*)alloc(768 * 4);
  __hip_bfloat16* xn   = (__hip_bfloat16*)alloc((size_t)ROWS * 768 * 2);   // also O after attention
  __hip_bfloat16* qkv  = (__hip_bfloat16*)alloc((size_t)ROWS * 2304 * 2);  // also xn2 + hbuf
  __hip_bfloat16* Obuf = xn;
  __hip_bfloat16* xn2  = qkv;
  __hip_bfloat16* hbuf = qkv + (size_t)ROWS * 768;  // 8224*3072 bf16 exactly

  // ---- weight / bias prep ----
  wprep<<<dim3(3, 2304), 256, 0, stream>>>(w_qkv, wqkv_t, 768, 2304, 0, gw);
  wprep<<<dim3(3, 768),  256, 0, stream>>>(w_proj, wproj_l, 768, 768, 0, gw);
  wprep<<<dim3(3, 768),  256, 0, stream>>>(w_proj, wproj_s, 768, 768, 1, gw);
  wprep<<<dim3(3, 3072), 256, 0, stream>>>(w_fc1, wfc1_t, 768, 3072, 0, gw);
  wprep<<<dim3(12, 768), 256, 0, stream>>>(w_fc2, wfc2_t, 3072, 768, 0, gw);
  bias_prep<<<3, 256, 0, stream>>>(b_proj, b_fc2, gw, b_small, b2_small);

  // ---- LN1 ----
  ln_k<<<ROWS / 4, 256, 0, stream>>>(x, xn, n1l_g, n1l_b, n1s_g, n1s_b);

  // ---- QKV (grid: x = n-group, y = m-group) ----
  gemm_k<<<dim3(18, 129), 256, 0, stream>>>(xn, 768, wqkv_t, 768, ROWS, 768,
                                            nullptr, nullptr, 0, gw, -1, nullptr,
                                            qkv, 2304, 0);
  // ---- attention (MFMA flash) ----
  attn_k<<<dim3(768, 5), 256, 0, stream>>>(qkv, Obuf);

  // ---- proj + residual -> x1 in d_out (fp32) ----
  gemm_k<<<dim3(6, 65), 256, 0, stream>>>(Obuf, 768, wproj_l, 768, B2ROWS, 768,
                                          b_proj, x, 768, gw, -1, nullptr, out, 768, 2);
  gemm_k<<<dim3(6, 65), 256, 0, stream>>>(Obuf + (size_t)B2ROWS * 768, 768, wproj_s, 768, B2ROWS, 768,
                                          b_small, x + (size_t)B2ROWS * 768, 768, gw, -1, nullptr,
                                          out + (size_t)B2ROWS * 768, 768, 2);

  // ---- LN2 on x1 (qkv region reused as xn2 + hbuf) ----
  ln_k<<<ROWS / 4, 256, 0, stream>>>(out, xn2, n2l_g, n2l_b, n2s_g, n2s_b);
  const __hip_bfloat16* xn2s = xn2 + (size_t)B2ROWS * 768;
  float* outs = out + (size_t)B2ROWS * 768;

  // ---- large MLP ----
  gemm_k<<<dim3(24, 65), 256, 0, stream>>>(xn2, 768, wfc1_t, 768, B2ROWS, 768,
                                           b_fc1, nullptr, 0, gw, -1, nullptr, hbuf, 3072, 1);
  gemm_k<<<dim3(6, 65), 256, 0, stream>>>(hbuf, 3072, wfc2_t, 3072, B2ROWS, 3072,
                                          b_fc2, out, 768, gw, -1, nullptr, out, 768, 2);

  // ---- small MLP: prefix chain in hbuf, FC2 per column slab ----
  gemm_k<<<dim3(24, 65), 256, 0, stream>>>(xn2s, 768, wfc1_t, 768, B2ROWS, 768,
                                           b_fc1, nullptr, 0, gw, 0, nullptr, hbuf, 3072, 1);
  gemm_k<<<dim3(3, 65), 256, 0, stream>>>(hbuf, 3072, wfc2_t + (size_t)384 * 3072, 3072, B2ROWS, 3072,
                                          b2_small + 384, outs + 384, 768, gw, -1, nullptr, outs + 384, 768, 2);
  gemm_k<<<dim3(24, 65), 256, 0, stream>>>(xn2s, 768, wfc1_t, 768, B2ROWS, 384,
                                           b_fc1, nullptr, 0, gw, 1, hbuf, hbuf, 3072, 1);
  gemm_k<<<dim3(1, 65), 256, 0, stream>>>(hbuf, 3072, wfc2_t + (size_t)256 * 3072, 3072, B2ROWS, 3072,
                                          b2_small + 256, outs + 256, 768, gw, -1, nullptr, outs + 256, 768, 2);
  gemm_k<<<dim3(24, 65), 256, 0, stream>>>(xn2s, 768, wfc1_t, 768, B2ROWS, 256,
                                           b_fc1, nullptr, 0, gw, 2, hbuf, hbuf, 3072, 1);
  gemm_k<<<dim3(2, 65), 256, 0, stream>>>(hbuf, 3072, wfc2_t, 3072, B2ROWS, 3072,
                                          b2_small, outs, 768, gw, -1, nullptr, outs, 768, 2);
}

// Round 6
// 1232.725 us; speedup vs baseline: 2.7109x; 1.0124x over previous
//
#include <hip/hip_runtime.h>
#include <hip/hip_bf16.h>

typedef short v8s __attribute__((ext_vector_type(8)));
typedef float v4f __attribute__((ext_vector_type(4)));

#define B2ROWS 8224   /* 32*257 */
#define ROWS   16448  /* 64*257 */

// ---------------- weight prep: transpose fp32 (K x N) -> bf16 (N x K) ----------------
__global__ __launch_bounds__(256) void wprep(const float* __restrict__ W,
                                             __hip_bfloat16* __restrict__ Wt,
                                             int K, int N, int variant,
                                             const float* __restrict__ gw) {
  int k = blockIdx.x * 256 + threadIdx.x;
  int n = blockIdx.y;
  if (k >= K) return;
  float v = W[(size_t)k * N + n];
  if (variant == 1) {
    int h = k >> 6;  // head index
    float s = gw[0];
    if (h < 6 && n < 384) s += gw[1];
    if (h < 4 && n < 256) s += gw[2];
    v *= s;
  }
  Wt[(size_t)n * K + k] = __float2bfloat16(v);
}

__global__ void bias_prep(const float* __restrict__ bp, const float* __restrict__ b2,
                          const float* __restrict__ gw,
                          float* __restrict__ b_small, float* __restrict__ b2_small) {
  int c = blockIdx.x * 256 + threadIdx.x;
  if (c >= 768) return;
  float s = gw[0] + (c < 384 ? gw[1] : 0.f) + (c < 256 ? gw[2] : 0.f);
  b_small[c] = bp[c] * s;
  b2_small[c] = b2[c] * s;
}

// ---------------- LayerNorm: fp32 in -> bf16 out, one row per wave ----------------
__global__ __launch_bounds__(256) void ln_k(const float* __restrict__ X,
                                            __hip_bfloat16* __restrict__ out,
                                            const float* __restrict__ gl, const float* __restrict__ bl,
                                            const float* __restrict__ gs, const float* __restrict__ bs) {
  int wave = threadIdx.x >> 6, lane = threadIdx.x & 63;
  int row = blockIdx.x * 4 + wave;
  const float* g = (row < B2ROWS) ? gl : gs;
  const float* b = (row < B2ROWS) ? bl : bs;
  const float* xr = X + (size_t)row * 768;
  float v[12]; float s = 0.f, ss = 0.f;
#pragma unroll
  for (int i = 0; i < 12; i++) { v[i] = xr[lane + i * 64]; s += v[i]; ss += v[i] * v[i]; }
#pragma unroll
  for (int o = 32; o > 0; o >>= 1) { s += __shfl_xor(s, o, 64); ss += __shfl_xor(ss, o, 64); }
  float mean = s * (1.0f / 768.0f);
  float var = ss * (1.0f / 768.0f) - mean * mean;
  float rstd = rsqrtf(var + 1e-5f);
  __hip_bfloat16* orow = out + (size_t)row * 768;
#pragma unroll
  for (int i = 0; i < 12; i++) {
    int c = lane + i * 64;
    orow[c] = __float2bfloat16((v[i] - mean) * rstd * g[c] + b[c]);
  }
}

// ---------------- bf16 MFMA GEMM: C(MxN) = A(MxK) * Bt(NxK)^T, 128x128 tile ----------------
// Round-5 body (known good: 0 bank conflicts, VGPR 76) with ONLY the staging
// swapped to global_load_lds width=16 (async DMA, no VGPR round-trip).
// Staging map per wave: lane -> (row = base + lane>>2, chunk q = lane&3);
// LDS dest = wave_base + lane*16 (lane-contiguous, as required); the XOR bank
// swizzle p = q^((r>>1)&3) is applied to the per-lane SOURCE k-offset, which
// is equivalent (XOR is an involution) and keeps the dest contiguous.
// blockIdx.x = n-group (fast) so co-resident blocks share A in L2/L3.
// mode 0: out bf16 = acc
// mode 1: out bf16 = scale*gelu(acc + bias) + (addin ? addin : 0)   (addin may alias out)
// mode 2: out fp32 = acc + bias + resid                             (resid may alias out)
__global__ __launch_bounds__(256) void gemm_k(
    const __hip_bfloat16* __restrict__ A, int lda,
    const __hip_bfloat16* __restrict__ Bt, int ldb,
    int M, int K,
    const float* __restrict__ bias,
    const float* __restrict__ resid, int ldr,
    const float* __restrict__ gw, int gidx,
    const __hip_bfloat16* __restrict__ addin,
    void* __restrict__ out, int ldo,
    int mode) {
  __shared__ __attribute__((aligned(16))) short As[128 * 32];
  __shared__ __attribute__((aligned(16))) short Bs[128 * 32];
  int tid = threadIdx.x;
  int lane = tid & 63;
  int wave = tid >> 6;
  int wm = wave >> 1, wn = wave & 1;
  int l16 = lane & 15, quad = lane >> 4;
  int m0 = blockIdx.y * 128, n0 = blockIdx.x * 128;
  int sw = (quad ^ ((l16 >> 1) & 3)) * 8;   // swizzled read chunk offset (shorts)

  // staging address components (per lane)
  int r4 = lane >> 2;                        // row within 16-row wave chunk
  int qs = (lane & 3) ^ ((r4 >> 1) & 3);     // swizzled SOURCE k-chunk

  v4f acc[4][4];
#pragma unroll
  for (int i = 0; i < 4; i++)
#pragma unroll
    for (int j = 0; j < 4; j++) acc[i][j] = (v4f){0.f, 0.f, 0.f, 0.f};

  const ushort* Au = (const ushort*)A;
  const ushort* Bu = (const ushort*)Bt;

  for (int k0 = 0; k0 < K; k0 += 32) {
    __syncthreads();
    // A: 128 rows x 4 chunks = 512 chunks; 2 wave-iterations x 4 waves x 64 lanes
#pragma unroll
    for (int it = 0; it < 2; it++) {
      int rbase = wave * 16 + it * 64;       // 16-row group staged by this wave
      int gr = m0 + rbase + r4; if (gr > M - 1) gr = M - 1;
      const void* gA = Au + (size_t)gr * lda + k0 + qs * 8;
      __builtin_amdgcn_global_load_lds(
          (const __attribute__((address_space(1))) uint32_t*)(uintptr_t)gA,
          (__attribute__((address_space(3))) uint32_t*)(uint32_t)(uintptr_t)(const void*)&As[rbase * 32],
          16, 0, 0);
      int gn = n0 + rbase + r4;              // N always a multiple of 128
      const void* gB = Bu + (size_t)gn * ldb + k0 + qs * 8;
      __builtin_amdgcn_global_load_lds(
          (const __attribute__((address_space(1))) uint32_t*)(uintptr_t)gB,
          (__attribute__((address_space(3))) uint32_t*)(uint32_t)(uintptr_t)(const void*)&Bs[rbase * 32],
          16, 0, 0);
    }
    __syncthreads();
    v8s af[4], bfr[4];
#pragma unroll
    for (int i = 0; i < 4; i++) af[i] = *(const v8s*)&As[(wm * 64 + i * 16 + l16) * 32 + sw];
#pragma unroll
    for (int j = 0; j < 4; j++) bfr[j] = *(const v8s*)&Bs[(wn * 64 + j * 16 + l16) * 32 + sw];
#pragma unroll
    for (int i = 0; i < 4; i++)
#pragma unroll
      for (int j = 0; j < 4; j++)
        acc[i][j] = __builtin_amdgcn_mfma_f32_16x16x32_bf16(af[i], bfr[j], acc[i][j], 0, 0, 0);
  }

  float scale = (gidx >= 0) ? gw[gidx] : 1.0f;

#pragma unroll
  for (int i = 0; i < 4; i++) {
#pragma unroll
    for (int j = 0; j < 4; j++) {
      int gc = n0 + wn * 64 + j * 16 + l16;
#pragma unroll
      for (int r = 0; r < 4; r++) {
        int gr = m0 + wm * 64 + i * 16 + quad * 4 + r;
        if (gr < M) {
          float v = acc[i][j][r];
          if (mode == 0) {
            ((__hip_bfloat16*)out)[(size_t)gr * ldo + gc] = __float2bfloat16(v);
          } else if (mode == 1) {
            float z = v + bias[gc];
            float gl = 0.5f * z * (1.0f + erff(z * 0.70710678118654752f));
            float res = scale * gl;
            if (addin) res += __bfloat162float(addin[(size_t)gr * ldo + gc]);
            ((__hip_bfloat16*)out)[(size_t)gr * ldo + gc] = __float2bfloat16(res);
          } else {
            float z = v + bias[gc] + resid[(size_t)gr * ldr + gc];
            ((float*)out)[(size_t)gr * ldo + gc] = z;
          }
        }
      }
    }
  }
}

// ---------------- MFMA flash attention (unchanged) ----------------
__global__ __launch_bounds__(256) void attn_k(const __hip_bfloat16* __restrict__ qkv,
                                              __hip_bfloat16* __restrict__ O) {
  __shared__ ushort Ks[64 * 72];
  __shared__ ushort Vs[64 * 64];
  __shared__ ushort Ps[4][16 * 72];
  int bh = blockIdx.x;
  int b = bh / 12, h = bh % 12;
  size_t base = (size_t)b * 257;
  const ushort* Qg = (const ushort*)qkv;
  int tid = threadIdx.x;
  int w = tid >> 6, lane = tid & 63;
  int l16 = lane & 15, quad = lane >> 4;
  int qrow0 = blockIdx.y * 64 + w * 16;

  v8s aq[2];
  {
    int gr = qrow0 + l16; if (gr > 256) gr = 256;
    const ushort* qp = Qg + (base + gr) * 2304 + h * 64;
    aq[0] = *(const v8s*)(qp + quad * 8);
    aq[1] = *(const v8s*)(qp + 32 + quad * 8);
  }

  float mrow[4], lrow[4];
  v4f o[4];
#pragma unroll
  for (int r = 0; r < 4; r++) { mrow[r] = -1e30f; lrow[r] = 0.f; }
#pragma unroll
  for (int dt = 0; dt < 4; dt++) o[dt] = (v4f){0.f, 0.f, 0.f, 0.f};

  for (int kt = 0; kt < 5; kt++) {
    __syncthreads();
#pragma unroll
    for (int it = 0; it < 2; it++) {
      int ch = tid + it * 256;
      int row = ch >> 3, oct = ch & 7;
      int gk = kt * 64 + row; if (gk > 256) gk = 256;
      *(uint4*)&Ks[row * 72 + oct * 8] =
        *(const uint4*)(Qg + (base + gk) * 2304 + 768 + h * 64 + oct * 8);
    }
#pragma unroll
    for (int it = 0; it < 2; it++) {
      int oct = w + it * 4;
      int gk = kt * 64 + lane; if (gk > 256) gk = 256;
      ushort tmp[8];
      *(uint4*)tmp = *(const uint4*)(Qg + (base + gk) * 2304 + 1536 + h * 64 + oct * 8);
#pragma unroll
      for (int j = 0; j < 8; j++) {
        int d = oct * 8 + j;
        Vs[d * 64 + (((lane >> 3) ^ j) * 8) + (lane & 7)] = tmp[j];
      }
    }
    __syncthreads();

    v4f s[4];
#pragma unroll
    for (int jt = 0; jt < 4; jt++) {
      v8s bk0 = *(const v8s*)&Ks[(jt * 16 + l16) * 72 + quad * 8];
      v8s bk1 = *(const v8s*)&Ks[(jt * 16 + l16) * 72 + 32 + quad * 8];
      v4f acc = (v4f){0.f, 0.f, 0.f, 0.f};
      acc = __builtin_amdgcn_mfma_f32_16x16x32_bf16(aq[0], bk0, acc, 0, 0, 0);
      acc = __builtin_amdgcn_mfma_f32_16x16x32_bf16(aq[1], bk1, acc, 0, 0, 0);
      s[jt] = acc;
    }
#pragma unroll
    for (int jt = 0; jt < 4; jt++) {
      int col = kt * 64 + jt * 16 + l16;
      bool valid = col < 257;
#pragma unroll
      for (int r = 0; r < 4; r++)
        s[jt][r] = valid ? s[jt][r] * 0.125f : -1e30f;
    }
    float mnew[4], alpha[4], psum[4];
#pragma unroll
    for (int r = 0; r < 4; r++) {
      float mx = fmaxf(fmaxf(s[0][r], s[1][r]), fmaxf(s[2][r], s[3][r]));
#pragma unroll
      for (int off = 1; off < 16; off <<= 1) mx = fmaxf(mx, __shfl_xor(mx, off, 64));
      mnew[r] = fmaxf(mrow[r], mx);
      alpha[r] = __expf(mrow[r] - mnew[r]);
      mrow[r] = mnew[r];
      psum[r] = 0.f;
    }
#pragma unroll
    for (int jt = 0; jt < 4; jt++) {
#pragma unroll
      for (int r = 0; r < 4; r++) {
        float p = __expf(s[jt][r] - mnew[r]);
        psum[r] += p;
        __hip_bfloat16 pb = __float2bfloat16(p);
        Ps[w][(quad * 4 + r) * 72 + jt * 16 + l16] = *(ushort*)&pb;
      }
    }
#pragma unroll
    for (int r = 0; r < 4; r++) {
#pragma unroll
      for (int off = 1; off < 16; off <<= 1) psum[r] += __shfl_xor(psum[r], off, 64);
      lrow[r] = lrow[r] * alpha[r] + psum[r];
    }
#pragma unroll
    for (int dt = 0; dt < 4; dt++)
#pragma unroll
      for (int r = 0; r < 4; r++) o[dt][r] *= alpha[r];
    v8s pa0 = *(const v8s*)&Ps[w][l16 * 72 + quad * 8];
    v8s pa1 = *(const v8s*)&Ps[w][l16 * 72 + 32 + quad * 8];
#pragma unroll
    for (int dt = 0; dt < 4; dt++) {
      int d = dt * 16 + l16;
      v8s bv0 = *(const v8s*)&Vs[d * 64 + ((quad ^ (d & 7)) * 8)];
      v8s bv1 = *(const v8s*)&Vs[d * 64 + (((4 + quad) ^ (d & 7)) * 8)];
      o[dt] = __builtin_amdgcn_mfma_f32_16x16x32_bf16(pa0, bv0, o[dt], 0, 0, 0);
      o[dt] = __builtin_amdgcn_mfma_f32_16x16x32_bf16(pa1, bv1, o[dt], 0, 0, 0);
    }
  }
#pragma unroll
  for (int r = 0; r < 4; r++) {
    int gr = qrow0 + quad * 4 + r;
    if (gr < 257) {
      float inv = 1.f / lrow[r];
      __hip_bfloat16* orow = O + (base + gr) * 768 + h * 64;
#pragma unroll
      for (int dt = 0; dt < 4; dt++)
        orow[dt * 16 + l16] = __float2bfloat16(o[dt][r] * inv);
    }
  }
}

extern "C" void kernel_launch(void* const* d_in, const int* in_sizes, int n_in,
                              void* d_out, int out_size, void* d_ws, size_t ws_size,
                              hipStream_t stream) {
  const float* x      = (const float*)d_in[0];
  const float* gw     = (const float*)d_in[1];
  const float* n1l_g  = (const float*)d_in[2];
  const float* n1l_b  = (const float*)d_in[3];
  const float* n1s_g  = (const float*)d_in[4];
  const float* n1s_b  = (const float*)d_in[5];
  const float* w_qkv  = (const float*)d_in[6];
  const float* w_proj = (const float*)d_in[7];
  const float* b_proj = (const float*)d_in[8];
  const float* n2l_g  = (const float*)d_in[9];
  const float* n2l_b  = (const float*)d_in[10];
  const float* n2s_g  = (const float*)d_in[11];
  const float* n2s_b  = (const float*)d_in[12];
  const float* w_fc1  = (const float*)d_in[13];
  const float* b_fc1  = (const float*)d_in[14];
  const float* w_fc2  = (const float*)d_in[15];
  const float* b_fc2  = (const float*)d_in[16];
  float* out = (float*)d_out;

  const size_t REQUIRED = (size_t)(2304*768 + 2*768*768 + 2*3072*768) * 2
                        + 2 * 768 * 4 + 512
                        + (size_t)ROWS * 768 * 2
                        + (size_t)ROWS * 2304 * 2;
  if (ws_size < REQUIRED) return;

  char* ws = (char*)d_ws;
  size_t off = 0;
  auto alloc = [&](size_t bytes) -> void* {
    void* p = ws + off;
    off = (off + bytes + 255) & ~(size_t)255;
    return p;
  };
  __hip_bfloat16* wqkv_t  = (__hip_bfloat16*)alloc((size_t)2304 * 768 * 2);
  __hip_bfloat16* wproj_l = (__hip_bfloat16*)alloc((size_t)768 * 768 * 2);
  __hip_bfloat16* wproj_s = (__hip_bfloat16*)alloc((size_t)768 * 768 * 2);
  __hip_bfloat16* wfc1_t  = (__hip_bfloat16*)alloc((size_t)3072 * 768 * 2);
  __hip_bfloat16* wfc2_t  = (__hip_bfloat16*)alloc((size_t)768 * 3072 * 2);
  float* b_small  = (float*)alloc(768 * 4);
  float* b2_small = (float*)alloc(768 * 4);
  __hip_bfloat16* xn   = (__hip_bfloat16*)alloc((size_t)ROWS * 768 * 2);   // also O after attention
  __hip_bfloat16* qkv  = (__hip_bfloat16*)alloc((size_t)ROWS * 2304 * 2);  // also xn2 + hbuf
  __hip_bfloat16* Obuf = xn;
  __hip_bfloat16* xn2  = qkv;
  __hip_bfloat16* hbuf = qkv + (size_t)ROWS * 768;  // 8224*3072 bf16 exactly

  // ---- weight / bias prep ----
  wprep<<<dim3(3, 2304), 256, 0, stream>>>(w_qkv, wqkv_t, 768, 2304, 0, gw);
  wprep<<<dim3(3, 768),  256, 0, stream>>>(w_proj, wproj_l, 768, 768, 0, gw);
  wprep<<<dim3(3, 768),  256, 0, stream>>>(w_proj, wproj_s, 768, 768, 1, gw);
  wprep<<<dim3(3, 3072), 256, 0, stream>>>(w_fc1, wfc1_t, 768, 3072, 0, gw);
  wprep<<<dim3(12, 768), 256, 0, stream>>>(w_fc2, wfc2_t, 3072, 768, 0, gw);
  bias_prep<<<3, 256, 0, stream>>>(b_proj, b_fc2, gw, b_small, b2_small);

  // ---- LN1 ----
  ln_k<<<ROWS / 4, 256, 0, stream>>>(x, xn, n1l_g, n1l_b, n1s_g, n1s_b);

  // ---- QKV (grid: x = n-group, y = m-group) ----
  gemm_k<<<dim3(18, 129), 256, 0, stream>>>(xn, 768, wqkv_t, 768, ROWS, 768,
                                            nullptr, nullptr, 0, gw, -1, nullptr,
                                            qkv, 2304, 0);
  // ---- attention (MFMA flash) ----
  attn_k<<<dim3(768, 5), 256, 0, stream>>>(qkv, Obuf);

  // ---- proj + residual -> x1 in d_out (fp32) ----
  gemm_k<<<dim3(6, 65), 256, 0, stream>>>(Obuf, 768, wproj_l, 768, B2ROWS, 768,
                                          b_proj, x, 768, gw, -1, nullptr, out, 768, 2);
  gemm_k<<<dim3(6, 65), 256, 0, stream>>>(Obuf + (size_t)B2ROWS * 768, 768, wproj_s, 768, B2ROWS, 768,
                                          b_small, x + (size_t)B2ROWS * 768, 768, gw, -1, nullptr,
                                          out + (size_t)B2ROWS * 768, 768, 2);

  // ---- LN2 on x1 (qkv region reused as xn2 + hbuf) ----
  ln_k<<<ROWS / 4, 256, 0, stream>>>(out, xn2, n2l_g, n2l_b, n2s_g, n2s_b);
  const __hip_bfloat16* xn2s = xn2 + (size_t)B2ROWS * 768;
  float* outs = out + (size_t)B2ROWS * 768;

  // ---- large MLP ----
  gemm_k<<<dim3(24, 65), 256, 0, stream>>>(xn2, 768, wfc1_t, 768, B2ROWS, 768,
                                           b_fc1, nullptr, 0, gw, -1, nullptr, hbuf, 3072, 1);
  gemm_k<<<dim3(6, 65), 256, 0, stream>>>(hbuf, 3072, wfc2_t, 3072, B2ROWS, 3072,
                                          b_fc2, out, 768, gw, -1, nullptr, out, 768, 2);

  // ---- small MLP: prefix chain in hbuf, FC2 per column slab ----
  gemm_k<<<dim3(24, 65), 256, 0, stream>>>(xn2s, 768, wfc1_t, 768, B2ROWS, 768,
                                           b_fc1, nullptr, 0, gw, 0, nullptr, hbuf, 3072, 1);
  gemm_k<<<dim3(3, 65), 256, 0, stream>>>(hbuf, 3072, wfc2_t + (size_t)384 * 3072, 3072, B2ROWS, 3072,
                                          b2_small + 384, outs + 384, 768, gw, -1, nullptr, outs + 384, 768, 2);
  gemm_k<<<dim3(24, 65), 256, 0, stream>>>(xn2s, 768, wfc1_t, 768, B2ROWS, 384,
                                           b_fc1, nullptr, 0, gw, 1, hbuf, hbuf, 3072, 1);
  gemm_k<<<dim3(1, 65), 256, 0, stream>>>(hbuf, 3072, wfc2_t + (size_t)256 * 3072, 3072, B2ROWS, 3072,
                                          b2_small + 256, outs + 256, 768, gw, -1, nullptr, outs + 256, 768, 2);
  gemm_k<<<dim3(24, 65), 256, 0, stream>>>(xn2s, 768, wfc1_t, 768, B2ROWS, 256,
                                           b_fc1, nullptr, 0, gw, 2, hbuf, hbuf, 3072, 1);
  gemm_k<<<dim3(2, 65), 256, 0, stream>>>(hbuf, 3072, wfc2_t, 3072, B2ROWS, 3072,
                                          b2_small, outs, 768, gw, -1, nullptr, outs, 768, 2);
}